// Round 5
// baseline (150.605 us; speedup 1.0000x reference)
//
#include <hip/hip_runtime.h>
#include <hip/hip_bf16.h>

// SocialPooling round 5: R4's dense MFMA scatter + 4x occupancy + swizzled roundtrip.
// Grid 512 x 512thr: block = (seq, half): 32 X-rows, all 64 cells. 8 waves =
// 2 row-tiles x 4 cell-groups; per wave: 16 rows x 16 cells, no barriers in loop.
// P roundtrip uses XOR chunk swizzle -> 2-way (free) LDS banks on b16 writes.

#define NSEQ 256
#define NPED 64
#define NTOT (NSEQ*NPED)
#define EPSV 1e-5f

typedef __attribute__((ext_vector_type(8))) short short8;
typedef __attribute__((ext_vector_type(4))) float f32x4;
typedef unsigned short ushort_t;

__device__ __forceinline__ ushort_t f2b(float f) {
    __hip_bfloat16 h = __float2bfloat16(f);                 // RNE
    return *reinterpret_cast<ushort_t*>(&h);
}

// ---------------- K0: transpose one W cell per block (verified R3/R4) ----------------
__global__ __launch_bounds__(256) void sp_transpose(
    const float* __restrict__ W, short* __restrict__ Wt)
{
    __shared__ __align__(16) float Tl[64*68];
    const int b = blockIdx.x, tid = threadIdx.x;
    const float* wg = W + (size_t)b*4096;
    for (int m = 0; m < 4; ++m) {
        int c = m*256 + tid;
        int k = c >> 4, t0 = (c & 15)*4;
        *(f32x4*)(Tl + k*68 + t0) = *(const f32x4*)(wg + k*64 + t0);
    }
    __syncthreads();
    for (int m = 0; m < 2; ++m) {
        int q = m*256 + tid;
        int col = q >> 3, k0 = (q & 7)*8;
        short8 o;
        #pragma unroll
        for (int i2 = 0; i2 < 8; ++i2)
            o[i2] = (short)f2b(Tl[(k0 + i2)*68 + col]);
        *(short8*)(Wt + ((size_t)(b*64 + col)*64 + k0)) = o;  // Wt[g][col][k]
    }
}

// ---------------- K1: main ----------------
// LDS carve (bytes):
#define SM_HT   0        // u16 Ht[64][72]                         9216
#define SM_PW   9216     // u16 Pw[8 waves][16][72] swizzled      18432 ; alias f32 Xs[32][68] 8704
#define SM_CM   27648    // u8 cm[64][64] 4096 ; alias f32 red1/red2 [4][64]x2 = 2048
#define SM_POS  31744    // f32 px[64], py[64]                      512
#define SM_TOT  32256

__global__ __launch_bounds__(512, 4) void sp_main(
    const float* __restrict__ h, const float* __restrict__ pos,
    const short* __restrict__ Wt, const float* __restrict__ bvec,
    float* __restrict__ X, float* __restrict__ partials)
{
    __shared__ __align__(16) char smem[SM_TOT];
    ushort_t*      Ht = (ushort_t*)(smem + SM_HT);
    unsigned char* cm = (unsigned char*)(smem + SM_CM);
    float*         px = (float*)(smem + SM_POS);
    float*         py = px + 64;

    const int b    = blockIdx.x;
    const int s    = b >> 1;            // sequence
    const int half = b & 1;             // row half: rows half*32 .. +31
    const int base = s * NPED;
    const int tid  = threadIdx.x;
    const int lane = tid & 63, w = tid >> 6;      // 8 waves
    const int rw   = w & 1;             // row-tile within half (16 rows)
    const int cw   = w >> 1;            // cell group (16 cells)
    const int ln15 = lane & 15, ln4 = lane >> 4;
    ushort_t* Ps = (ushort_t*)(smem + SM_PW) + w*1152;   // wave slice [16][72] u16

    if (tid < 64) { px[tid] = pos[(base + tid)*2]; py[tid] = pos[(base + tid)*2 + 1]; }
    // stage H transposed: Ht[kf][j] = bf16(H[j][kf])
    for (int m = 0; m < 2; ++m) {
        int c = m*512 + tid;                             // 1024 f32x4 chunks
        int j = c >> 4, t0 = (c & 15)*4;
        f32x4 v = *(const f32x4*)(h + (size_t)(base + j)*64 + t0);
        #pragma unroll
        for (int u = 0; u < 4; ++u) Ht[(t0 + u)*72 + j] = f2b(v[u]);
    }
    __syncthreads();

    // cellmap: cm[i][j] = cell 0..63 if valid pair else 255 (same math as R1/R3/R4)
    for (int m = 0; m < 8; ++m) {
        int p = m*512 + tid;
        int i = p >> 6, j = p & 63;
        unsigned char val = 255;
        if (i != j) {
            float ax = px[i], ay = py[i], ox = px[j], oy = py[j];
            float tlx = ax - 1.0f, tly = ay + 1.0f, brx = ax + 1.0f, bry = ay - 1.0f;
            bool oob = (ox >= brx) | (ox <= tlx) | (oy >= tly) | (oy <= bry);
            if (!oob) {
                int g = (int)(floorf((ox - tlx)*4.0f) + floorf((tly - oy)*4.0f)*8.0f);
                g = g < 0 ? 0 : (g > 63 ? 63 : g);
                val = (unsigned char)g;
            }
        }
        cm[i*64 + j] = val;
    }
    __syncthreads();

    // hoisted GEMM1 B-frags (H): B[k=j][n=kf]
    short8 hf[2][4];
    #pragma unroll
    for (int kt = 0; kt < 2; ++kt)
        #pragma unroll
        for (int nt = 0; nt < 4; ++nt)
            hf[kt][nt] = *(const short8*)(Ht + (nt*16 + ln15)*72 + kt*32 + ln4*8);
    // hoisted cellmap for this wave's X rows: i = half*32 + rw*16 + ln15
    const int irow = half*32 + rw*16 + ln15;
    unsigned cmv[2][2];
    #pragma unroll
    for (int kt = 0; kt < 2; ++kt) {
        const unsigned* cp = (const unsigned*)(cm + irow*64 + kt*32 + ln4*8);
        cmv[kt][0] = cp[0]; cmv[kt][1] = cp[1];
    }

    f32x4 acc[4];
    #pragma unroll
    for (int nt = 0; nt < 4; ++nt) acc[nt] = (f32x4){0.f,0.f,0.f,0.f};

    const int sA = (ln15 >> 1) & 7;                      // read-side swizzle key
    for (int c = 0; c < 16; ++c) {
        const int g = cw*16 + c;
        // GEMM2 B-frags from Wt (L2/L1-resident; 4 rw-waves share -> L1 hits)
        const short* wg = Wt + (size_t)g*4096;
        short8 bw[2][4];
        #pragma unroll
        for (int kt = 0; kt < 2; ++kt)
            #pragma unroll
            for (int nt = 0; nt < 4; ++nt)
                bw[kt][nt] = *(const short8*)(wg + (nt*16 + ln15)*64 + kt*32 + ln4*8);

        // S-frags: S[i][j] = (cm[i][j]==g) as bf16 1.0/0.0
        short8 sf[2];
        #pragma unroll
        for (int kt = 0; kt < 2; ++kt)
            #pragma unroll
            for (int u = 0; u < 8; ++u) {
                unsigned byte = ((u < 4 ? cmv[kt][0] >> (8*u) : cmv[kt][1] >> (8*(u-4))) & 255u);
                sf[kt][u] = (byte == (unsigned)g) ? (short)0x3F80 : (short)0;
            }
        // GEMM1: P(16 rows x 64 kf) = S @ H, f32 acc
        f32x4 pt[4];
        #pragma unroll
        for (int nt = 0; nt < 4; ++nt) pt[nt] = (f32x4){0.f,0.f,0.f,0.f};
        #pragma unroll
        for (int kt = 0; kt < 2; ++kt)
            #pragma unroll
            for (int nt = 0; nt < 4; ++nt)
                pt[nt] = __builtin_amdgcn_mfma_f32_16x16x32_bf16(sf[kt], hf[kt][nt], pt[nt], 0, 0, 0);
        // roundtrip C->A layout via swizzled LDS (wave-private slice, no barrier)
        // write P[lr][col] at chunk (col>>3)^((lr>>1)&7), offset col&7
        #pragma unroll
        for (int nt = 0; nt < 4; ++nt)
            #pragma unroll
            for (int r = 0; r < 4; ++r) {
                int lr  = ln4*4 + r;
                int col = nt*16 + ln15;
                int cc  = (col >> 3) ^ ((lr >> 1) & 7);
                Ps[lr*72 + cc*8 + (col & 7)] = f2b(pt[nt][r]);
            }
        short8 af0 = *(const short8*)(Ps + ln15*72 + ((ln4    ) ^ sA)*8);  // kt=0: cc=ln4
        short8 af1 = *(const short8*)(Ps + ln15*72 + ((4 + ln4) ^ sA)*8);  // kt=1: cc=4+ln4
        // GEMM2: X(16 rows) += P @ W_g
        #pragma unroll
        for (int nt = 0; nt < 4; ++nt) {
            acc[nt] = __builtin_amdgcn_mfma_f32_16x16x32_bf16(af0, bw[0][nt], acc[nt], 0, 0, 0);
            acc[nt] = __builtin_amdgcn_mfma_f32_16x16x32_bf16(af1, bw[1][nt], acc[nt], 0, 0, 0);
        }
    }
    __syncthreads();                                     // all Pw/cm reads done

    // combine 4 cell-groups into Xs[32][68] f32 (aliases Pw)
    float* Xs = (float*)(smem + SM_PW);
    for (int cwv = 0; cwv < 4; ++cwv) {
        if (cw == cwv) {
            #pragma unroll
            for (int nt = 0; nt < 4; ++nt)
                #pragma unroll
                for (int r = 0; r < 4; ++r) {
                    int row_l = rw*16 + ln4*4 + r;       // C/D: col=lane&15, row=(lane>>4)*4+reg
                    int col   = nt*16 + ln15;
                    if (cwv == 0) Xs[row_l*68 + col]  = acc[nt][r];
                    else          Xs[row_l*68 + col] += acc[nt][r];
                }
        }
        __syncthreads();
    }

    // write X + bias (f32x4 coalesced)
    {
        const int row_l = tid >> 4, c0 = (tid & 15)*4;
        f32x4 v;
        #pragma unroll
        for (int u = 0; u < 4; ++u) v[u] = Xs[row_l*68 + c0 + u] + bvec[c0 + u];
        *(f32x4*)(X + (size_t)(base + half*32 + row_l)*64 + c0) = v;
    }

    // per-block column sum / sumsq (with bias) over 32 rows
    {
        float* red1 = (float*)(smem + SM_CM);            // aliases cm (done)
        float* red2 = red1 + 256;
        if (tid < 256) {
            int col = tid & 63, rg = tid >> 6;
            float bc = bvec[col], s1 = 0.f, s2 = 0.f;
            for (int ii = 0; ii < 8; ++ii) {
                float xv = Xs[(rg*8 + ii)*68 + col] + bc;
                s1 += xv; s2 += xv*xv;
            }
            red1[rg*64 + col] = s1;
            red2[rg*64 + col] = s2;
        }
        __syncthreads();
        if (tid < 128) {
            int hs = tid >> 6, c2 = tid & 63;
            const float* r0 = hs ? red2 : red1;
            float v = r0[c2] + r0[64 + c2] + r0[128 + c2] + r0[192 + c2];
            partials[(size_t)b*128 + hs*64 + c2] = v;    // [block][slot]
        }
    }
}

// ---------------- K2: redundant stats reduce + normalize + ReLU ----------------
__global__ __launch_bounds__(256) void sp_finish(
    float* __restrict__ X, const float* __restrict__ partials,
    const float* __restrict__ gamma, const float* __restrict__ beta)
{
    __shared__ float sp0[128], sp1[128];
    __shared__ float scale[64], shift[64];
    const int b = blockIdx.x, tid = threadIdx.x;

    {   // sum 512 block-partials; threads split the block range in half
        const int slot = tid & 127, hb = tid >> 7;
        float v = 0.f;
        const float* p = partials + (size_t)hb*256*128 + slot;
        #pragma unroll 4
        for (int bb = 0; bb < 256; ++bb) v += p[(size_t)bb*128];
        (hb ? sp1 : sp0)[slot] = v;
    }
    __syncthreads();
    if (tid < 64) {
        const float inv_n = 1.0f / (float)NTOT;
        float s1 = sp0[tid] + sp1[tid];
        float s2 = sp0[64 + tid] + sp1[64 + tid];
        float mu  = s1 * inv_n;
        float var = s2 * inv_n - mu*mu;
        float sc  = gamma[tid] / sqrtf(var + EPSV);
        scale[tid] = sc;
        shift[tid] = beta[tid] - mu*sc;
    }
    __syncthreads();
    #pragma unroll
    for (int q = 0; q < 4; ++q) {
        size_t idx4 = (size_t)b*1024 + q*256 + tid;      // f32x4 units
        f32x4 v = ((f32x4*)X)[idx4];
        int c0 = ((int)idx4*4) & 63;
        #pragma unroll
        for (int u = 0; u < 4; ++u)
            v[u] = fmaxf(v[u]*scale[c0 + u] + shift[c0 + u], 0.0f);
        ((f32x4*)X)[idx4] = v;
    }
}

extern "C" void kernel_launch(void* const* d_in, const int* in_sizes, int n_in,
                              void* d_out, int out_size, void* d_ws, size_t ws_size,
                              hipStream_t stream)
{
    const float* h     = (const float*)d_in[0];
    // d_in[1] seq_start_end: provably uniform (reference only uses N//nseq)
    const float* pos   = (const float*)d_in[2];
    const float* W     = (const float*)d_in[3];
    const float* bvec  = (const float*)d_in[4];
    const float* gamma = (const float*)d_in[5];
    const float* beta  = (const float*)d_in[6];

    float* X        = (float*)d_out;
    short* Wt       = (short*)d_ws;                      // 512 KB bf16 W^T
    float* partials = (float*)((char*)d_ws + 524288);    // 512*128*4 = 256 KB

    sp_transpose<<<64,  256, 0, stream>>>(W, Wt);
    sp_main     <<<512, 512, 0, stream>>>(h, pos, Wt, bvec, X, partials);
    sp_finish   <<<NSEQ, 256, 0, stream>>>(X, partials, gamma, beta);
}

// Round 6
// 150.392 us; speedup vs baseline: 1.0014x; 1.0014x over previous
//
#include <hip/hip_runtime.h>
#include <hip/hip_bf16.h>

// SocialPooling round 6: LDS-roundtrip-free MFMA scatter.
// GEMM1' computes P^T = Ht @ S^T so the output lane mapping (lane=i) already
// matches GEMM2's A-frag; W is stored with k-rows permuted by pi(k) so the
// A-frag is a pure in-lane register reshuffle of GEMM1' output. The per-cell
// loop has ZERO LDS instructions (R5's 16 ds_write_b16 + lgkm drain + ds_read
// per cell was the invariant per-CU bottleneck: R4 and R5 both ~66us).
// pi(k) = ((k>>5)*2 + ((k&7)>>2))*16 + ((k>>3)&3)*4 + (k&3)   (bijective)

#define NSEQ 256
#define NPED 64
#define NTOT (NSEQ*NPED)
#define EPSV 1e-5f

typedef __attribute__((ext_vector_type(8))) short short8;
typedef __attribute__((ext_vector_type(4))) float f32x4;
typedef unsigned short ushort_t;

__device__ __forceinline__ ushort_t f2b(float f) {
    __hip_bfloat16 h = __float2bfloat16(f);                 // RNE
    return *reinterpret_cast<ushort_t*>(&h);
}
__device__ __forceinline__ int kperm(int k) {               // slot -> source kf
    return ((k >> 5)*2 + ((k & 7) >> 2))*16 + ((k >> 3) & 3)*4 + (k & 3);
}

// ---------------- K0: W -> bf16 Wt'[g][col][slot] = W[g*64 + pi(slot)][col] ----------------
__global__ __launch_bounds__(256) void sp_transpose(
    const float* __restrict__ W, short* __restrict__ Wt)
{
    __shared__ __align__(16) float Tl[64*68];
    const int b = blockIdx.x, tid = threadIdx.x;
    const float* wg = W + (size_t)b*4096;
    for (int m = 0; m < 4; ++m) {
        int c = m*256 + tid;
        int k = c >> 4, t0 = (c & 15)*4;
        *(f32x4*)(Tl + k*68 + t0) = *(const f32x4*)(wg + k*64 + t0);
    }
    __syncthreads();
    for (int m = 0; m < 2; ++m) {
        int q = m*256 + tid;
        int col = q >> 3, k0 = (q & 7)*8;
        short8 o;
        #pragma unroll
        for (int i2 = 0; i2 < 8; ++i2)
            o[i2] = (short)f2b(Tl[kperm(k0 + i2)*68 + col]);   // permuted k rows
        *(short8*)(Wt + ((size_t)(b*64 + col)*64 + k0)) = o;
    }
}

// ---------------- K1: main ----------------
// LDS carve (bytes):
#define SM_HT   0        // u16 Ht[64][72] 9216 ; alias f32 Xs[32][68] 8704
#define SM_CM   9216     // u8 cm[64][64] 4096 ; alias f32 red1/red2 [4][64]x2 2048
#define SM_POS  13312    // f32 px[64], py[64] 512
#define SM_TOT  13824

__global__ __launch_bounds__(512, 4) void sp_main(
    const float* __restrict__ h, const float* __restrict__ pos,
    const short* __restrict__ Wt, const float* __restrict__ bvec,
    float* __restrict__ X, float* __restrict__ partials)
{
    __shared__ __align__(16) char smem[SM_TOT];
    ushort_t*      Ht = (ushort_t*)(smem + SM_HT);
    unsigned char* cm = (unsigned char*)(smem + SM_CM);
    float*         px = (float*)(smem + SM_POS);
    float*         py = px + 64;

    const int b    = blockIdx.x;
    const int s    = b >> 1;            // sequence
    const int half = b & 1;             // row half: rows half*32 .. +31
    const int base = s * NPED;
    const int tid  = threadIdx.x;
    const int lane = tid & 63, w = tid >> 6;      // 8 waves
    const int rw   = w & 1;             // row-tile within half (16 rows)
    const int cw   = w >> 1;            // cell group (16 cells)
    const int ln15 = lane & 15, ln4 = lane >> 4;

    if (tid < 64) { px[tid] = pos[(base + tid)*2]; py[tid] = pos[(base + tid)*2 + 1]; }
    // stage H transposed: Ht[kf][j] = bf16(H[j][kf])
    for (int m = 0; m < 2; ++m) {
        int c = m*512 + tid;
        int j = c >> 4, t0 = (c & 15)*4;
        f32x4 v = *(const f32x4*)(h + (size_t)(base + j)*64 + t0);
        #pragma unroll
        for (int u = 0; u < 4; ++u) Ht[(t0 + u)*72 + j] = f2b(v[u]);
    }
    __syncthreads();

    // cellmap: cm[i][j] = cell 0..63 if valid pair else 255 (verified math R1..R5)
    for (int m = 0; m < 8; ++m) {
        int p = m*512 + tid;
        int i = p >> 6, j = p & 63;
        unsigned char val = 255;
        if (i != j) {
            float ax = px[i], ay = py[i], ox = px[j], oy = py[j];
            float tlx = ax - 1.0f, tly = ay + 1.0f, brx = ax + 1.0f, bry = ay - 1.0f;
            bool oob = (ox >= brx) | (ox <= tlx) | (oy >= tly) | (oy <= bry);
            if (!oob) {
                int g = (int)(floorf((ox - tlx)*4.0f) + floorf((tly - oy)*4.0f)*8.0f);
                g = g < 0 ? 0 : (g > 63 ? 63 : g);
                val = (unsigned char)g;
            }
        }
        cm[i*64 + j] = val;
    }
    __syncthreads();

    // hoisted GEMM1' A-frags: A[m=kf][k=j] = H^T rows (4 m-tiles x 2 k-chunks)
    short8 hf2[4][2];
    #pragma unroll
    for (int mt = 0; mt < 4; ++mt)
        #pragma unroll
        for (int kt2 = 0; kt2 < 2; ++kt2)
            hf2[mt][kt2] = *(const short8*)(Ht + (mt*16 + ln15)*72 + kt2*32 + ln4*8);
    // hoisted cellmap for this wave's i rows: i = half*32 + rw*16 + ln15
    const int irow = half*32 + rw*16 + ln15;
    unsigned cmv[2][2];
    #pragma unroll
    for (int kt = 0; kt < 2; ++kt) {
        const unsigned* cp = (const unsigned*)(cm + irow*64 + kt*32 + ln4*8);
        cmv[kt][0] = cp[0]; cmv[kt][1] = cp[1];
    }

    f32x4 acc[4];
    #pragma unroll
    for (int nt = 0; nt < 4; ++nt) acc[nt] = (f32x4){0.f,0.f,0.f,0.f};

    for (int c = 0; c < 16; ++c) {
        const int g = cw*16 + c;
        const short* wg = Wt + (size_t)g*4096;
        // S^T B-frags: B[k=j][n=i] = (cm[i][j]==g), bf16 1.0/0.0
        short8 sf[2];
        #pragma unroll
        for (int kt = 0; kt < 2; ++kt)
            #pragma unroll
            for (int u = 0; u < 8; ++u) {
                unsigned byte = ((u < 4 ? cmv[kt][0] >> (8*u) : cmv[kt][1] >> (8*(u-4))) & 255u);
                sf[kt][u] = (byte == (unsigned)g) ? (short)0x3F80 : (short)0;
            }
        // GEMM1': P^T tiles, D[m=kf][n=i]: lane=i, regs kf = mt*16 + ln4*4 + r
        f32x4 pt[4];
        #pragma unroll
        for (int mt = 0; mt < 4; ++mt) pt[mt] = (f32x4){0.f,0.f,0.f,0.f};
        #pragma unroll
        for (int kt2 = 0; kt2 < 2; ++kt2)
            #pragma unroll
            for (int mt = 0; mt < 4; ++mt)
                pt[mt] = __builtin_amdgcn_mfma_f32_16x16x32_bf16(hf2[mt][kt2], sf[kt2], pt[mt], 0, 0, 0);
        // GEMM2: A-frag = in-lane reshuffle (pi-permuted W makes this exact)
        #pragma unroll
        for (int kt = 0; kt < 2; ++kt) {
            short8 af;
            #pragma unroll
            for (int r = 0; r < 4; ++r) {
                af[r]     = (short)f2b(pt[2*kt    ][r]);
                af[4 + r] = (short)f2b(pt[2*kt + 1][r]);
            }
            #pragma unroll
            for (int nt = 0; nt < 4; ++nt) {
                short8 bw = *(const short8*)(wg + (nt*16 + ln15)*64 + kt*32 + ln4*8);
                acc[nt] = __builtin_amdgcn_mfma_f32_16x16x32_bf16(af, bw, acc[nt], 0, 0, 0);
            }
        }
    }
    __syncthreads();                                     // all Ht/cm reads done

    // combine 4 cell-groups into Xs[32][68] f32 (aliases Ht)
    float* Xs = (float*)(smem + SM_HT);
    for (int cwv = 0; cwv < 4; ++cwv) {
        if (cw == cwv) {
            #pragma unroll
            for (int nt = 0; nt < 4; ++nt)
                #pragma unroll
                for (int r = 0; r < 4; ++r) {
                    int row_l = rw*16 + ln4*4 + r;       // C/D: col=lane&15, row=(lane>>4)*4+reg
                    int col   = nt*16 + ln15;
                    if (cwv == 0) Xs[row_l*68 + col]  = acc[nt][r];
                    else          Xs[row_l*68 + col] += acc[nt][r];
                }
        }
        __syncthreads();
    }

    // write X + bias (f32x4 coalesced)
    {
        const int row_l = tid >> 4, c0 = (tid & 15)*4;
        f32x4 v;
        #pragma unroll
        for (int u = 0; u < 4; ++u) v[u] = Xs[row_l*68 + c0 + u] + bvec[c0 + u];
        *(f32x4*)(X + (size_t)(base + half*32 + row_l)*64 + c0) = v;
    }

    // per-block column sum / sumsq (with bias) over 32 rows
    {
        float* red1 = (float*)(smem + SM_CM);            // aliases cm (done)
        float* red2 = red1 + 256;
        if (tid < 256) {
            int col = tid & 63, rg = tid >> 6;
            float bc = bvec[col], s1 = 0.f, s2 = 0.f;
            for (int ii = 0; ii < 8; ++ii) {
                float xv = Xs[(rg*8 + ii)*68 + col] + bc;
                s1 += xv; s2 += xv*xv;
            }
            red1[rg*64 + col] = s1;
            red2[rg*64 + col] = s2;
        }
        __syncthreads();
        if (tid < 128) {
            int hs = tid >> 6, c2 = tid & 63;
            const float* r0 = hs ? red2 : red1;
            float v = r0[c2] + r0[64 + c2] + r0[128 + c2] + r0[192 + c2];
            partials[(size_t)b*128 + hs*64 + c2] = v;    // [block][slot]
        }
    }
}

// ---------------- K2: redundant stats reduce + normalize + ReLU ----------------
__global__ __launch_bounds__(256) void sp_finish(
    float* __restrict__ X, const float* __restrict__ partials,
    const float* __restrict__ gamma, const float* __restrict__ beta)
{
    __shared__ float sp0[128], sp1[128];
    __shared__ float scale[64], shift[64];
    const int b = blockIdx.x, tid = threadIdx.x;

    {   // sum 512 block-partials; threads split the block range in half
        const int slot = tid & 127, hb = tid >> 7;
        float v = 0.f;
        const float* p = partials + (size_t)hb*256*128 + slot;
        #pragma unroll 4
        for (int bb = 0; bb < 256; ++bb) v += p[(size_t)bb*128];
        (hb ? sp1 : sp0)[slot] = v;
    }
    __syncthreads();
    if (tid < 64) {
        const float inv_n = 1.0f / (float)NTOT;
        float s1 = sp0[tid] + sp1[tid];
        float s2 = sp0[64 + tid] + sp1[64 + tid];
        float mu  = s1 * inv_n;
        float var = s2 * inv_n - mu*mu;
        float sc  = gamma[tid] / sqrtf(var + EPSV);
        scale[tid] = sc;
        shift[tid] = beta[tid] - mu*sc;
    }
    __syncthreads();
    #pragma unroll
    for (int q = 0; q < 4; ++q) {
        size_t idx4 = (size_t)b*1024 + q*256 + tid;      // f32x4 units
        f32x4 v = ((f32x4*)X)[idx4];
        int c0 = ((int)idx4*4) & 63;
        #pragma unroll
        for (int u = 0; u < 4; ++u)
            v[u] = fmaxf(v[u]*scale[c0 + u] + shift[c0 + u], 0.0f);
        ((f32x4*)X)[idx4] = v;
    }
}

extern "C" void kernel_launch(void* const* d_in, const int* in_sizes, int n_in,
                              void* d_out, int out_size, void* d_ws, size_t ws_size,
                              hipStream_t stream)
{
    const float* h     = (const float*)d_in[0];
    // d_in[1] seq_start_end: provably uniform (reference only uses N//nseq)
    const float* pos   = (const float*)d_in[2];
    const float* W     = (const float*)d_in[3];
    const float* bvec  = (const float*)d_in[4];
    const float* gamma = (const float*)d_in[5];
    const float* beta  = (const float*)d_in[6];

    float* X        = (float*)d_out;
    short* Wt       = (short*)d_ws;                      // 512 KB bf16 W' (k-permuted)
    float* partials = (float*)((char*)d_ws + 524288);    // 512*128*4 = 256 KB

    sp_transpose<<<64,  256, 0, stream>>>(W, Wt);
    sp_main     <<<512, 512, 0, stream>>>(h, pos, Wt, bvec, X, partials);
    sp_finish   <<<NSEQ, 256, 0, stream>>>(X, partials, gamma, beta);
}

// Round 7
// 117.155 us; speedup vs baseline: 1.2855x; 1.2837x over previous
//
#include <hip/hip_runtime.h>
#include <hip/hip_bf16.h>

// SocialPooling round 7: L2-hotspot fix.
// Evidence: R4/R5/R6 (different VALU/LDS/occupancy) all = 65-66us with 512MB of
// L2 reads of a 512KB Wt region in block-lockstep cell order => L2 channel
// hotspot at ~23% of L2 BW. Fix: (a) wave owns 8 cells x ALL 64 rows so each
// bw fragment set is reused for 4 row-tiles (Wt traffic 512MB -> 128MB);
// (b) per-block cell-order stagger (c+b)&7 so all 64 cells are hot at once.
// Numerics identical to R6 (pi-permuted Wt, GEMM1' P^T = Ht @ S^T, in-lane
// reshuffle, f32 stats) -- absmax expected unchanged at 0.03125.

#define NSEQ 256
#define NTOT (NSEQ*64)
#define EPSV 1e-5f

typedef __attribute__((ext_vector_type(8))) short short8;
typedef __attribute__((ext_vector_type(4))) float f32x4;
typedef unsigned short ushort_t;

__device__ __forceinline__ ushort_t f2b(float f) {
    __hip_bfloat16 h = __float2bfloat16(f);                 // RNE
    return *reinterpret_cast<ushort_t*>(&h);
}
__device__ __forceinline__ int kperm(int k) {               // slot -> source kf
    return ((k >> 5)*2 + ((k & 7) >> 2))*16 + ((k >> 3) & 3)*4 + (k & 3);
}

// ---------------- K0: W -> bf16 Wt'[g][col][slot] = W[g*64 + pi(slot)][col] ----------------
__global__ __launch_bounds__(256) void sp_transpose(
    const float* __restrict__ W, short* __restrict__ Wt)
{
    __shared__ __align__(16) float Tl[64*68];
    const int b = blockIdx.x, tid = threadIdx.x;
    const float* wg = W + (size_t)b*4096;
    for (int m = 0; m < 4; ++m) {
        int c = m*256 + tid;
        int k = c >> 4, t0 = (c & 15)*4;
        *(f32x4*)(Tl + k*68 + t0) = *(const f32x4*)(wg + k*64 + t0);
    }
    __syncthreads();
    for (int m = 0; m < 2; ++m) {
        int q = m*256 + tid;
        int col = q >> 3, k0 = (q & 7)*8;
        short8 o;
        #pragma unroll
        for (int i2 = 0; i2 < 8; ++i2)
            o[i2] = (short)f2b(Tl[kperm(k0 + i2)*68 + col]);
        *(short8*)(Wt + ((size_t)(b*64 + col)*64 + k0)) = o;
    }
}

// ---------------- K1: main ----------------
// LDS: staging {Ht u16[64][72]@0 9216, cm u8[64][64]@9216 4096, pos@13312 512}
//      aliased by epilogue {Xs f32[64][68]@0 17408, red f32[2][4][64]@17408 2048}
#define SM_CM   9216
#define SM_POS  13312
#define SM_RED  17408
#define SM_TOT  19456

__global__ __launch_bounds__(512, 2) void sp_main(
    const float* __restrict__ h, const float* __restrict__ pos,
    const short* __restrict__ Wt, const float* __restrict__ bvec,
    float* __restrict__ X, float* __restrict__ partials)
{
    __shared__ __align__(16) char smem[SM_TOT];
    ushort_t*      Ht = (ushort_t*)(smem);
    unsigned char* cm = (unsigned char*)(smem + SM_CM);
    float*         px = (float*)(smem + SM_POS);
    float*         py = px + 64;

    const int b    = blockIdx.x;        // sequence
    const int base = b * 64;
    const int tid  = threadIdx.x;
    const int lane = tid & 63, w = tid >> 6;      // 8 waves; wave owns cells w*8..w*8+7
    const int ln15 = lane & 15, ln4 = lane >> 4;

    if (tid < 64) { px[tid] = pos[(base + tid)*2]; py[tid] = pos[(base + tid)*2 + 1]; }
    // stage H transposed: Ht[kf][j] = bf16(H[j][kf])
    for (int m = 0; m < 2; ++m) {
        int c = m*512 + tid;
        int j = c >> 4, t0 = (c & 15)*4;
        f32x4 v = *(const f32x4*)(h + (size_t)(base + j)*64 + t0);
        #pragma unroll
        for (int u = 0; u < 4; ++u) Ht[(t0 + u)*72 + j] = f2b(v[u]);
    }
    __syncthreads();

    // cellmap: cm[i][j] = cell 0..63 if valid pair else 255 (verified R1..R6)
    for (int m = 0; m < 8; ++m) {
        int p = m*512 + tid;
        int i = p >> 6, j = p & 63;
        unsigned char val = 255;
        if (i != j) {
            float ax = px[i], ay = py[i], ox = px[j], oy = py[j];
            float tlx = ax - 1.0f, tly = ay + 1.0f, brx = ax + 1.0f, bry = ay - 1.0f;
            bool oob = (ox >= brx) | (ox <= tlx) | (oy >= tly) | (oy <= bry);
            if (!oob) {
                int g = (int)(floorf((ox - tlx)*4.0f) + floorf((tly - oy)*4.0f)*8.0f);
                g = g < 0 ? 0 : (g > 63 ? 63 : g);
                val = (unsigned char)g;
            }
        }
        cm[i*64 + j] = val;
    }
    __syncthreads();

    // hoist GEMM1' A-frags (H^T rows): A[m=kf=mt*16+ln15][k=j=kt2*32+ln4*8+u]
    short8 hf2[4][2];
    #pragma unroll
    for (int mt = 0; mt < 4; ++mt)
        #pragma unroll
        for (int kt2 = 0; kt2 < 2; ++kt2)
            hf2[mt][kt2] = *(const short8*)(Ht + (mt*16 + ln15)*72 + kt2*32 + ln4*8);
    // hoist cellmap for ALL 64 i-rows: cmv[rt][kt2][word], i = rt*16+ln15
    unsigned cmv[4][2][2];
    #pragma unroll
    for (int rt = 0; rt < 4; ++rt)
        #pragma unroll
        for (int kt = 0; kt < 2; ++kt) {
            const unsigned* cp = (const unsigned*)(cm + (rt*16 + ln15)*64 + kt*32 + ln4*8);
            cmv[rt][kt][0] = cp[0]; cmv[rt][kt][1] = cp[1];
        }

    f32x4 acc[4][4];                    // [rt][nt] -- full 64 rows x 64 cols partial
    #pragma unroll
    for (int rt = 0; rt < 4; ++rt)
        #pragma unroll
        for (int nt = 0; nt < 4; ++nt) acc[rt][nt] = (f32x4){0.f,0.f,0.f,0.f};

    for (int c = 0; c < 8; ++c) {
        const int g = w*8 + ((c + b) & 7);          // per-block stagger: decorrelate L2 lines
        const short* wg = Wt + (size_t)g*4096;
        // issue all 8 Wt b128 loads up front; GEMM1'/sf work below hides L2 latency
        short8 bw[2][4];
        #pragma unroll
        for (int kt = 0; kt < 2; ++kt)
            #pragma unroll
            for (int nt = 0; nt < 4; ++nt)
                bw[kt][nt] = *(const short8*)(wg + (nt*16 + ln15)*64 + kt*32 + ln4*8);

        #pragma unroll
        for (int rt = 0; rt < 4; ++rt) {
            // S^T B-frags for row-tile rt: B[k=j][n=i=rt*16+ln15] = (cm[i][j]==g)
            short8 sf[2];
            #pragma unroll
            for (int kt = 0; kt < 2; ++kt)
                #pragma unroll
                for (int u = 0; u < 8; ++u) {
                    unsigned byte = ((u < 4 ? cmv[rt][kt][0] >> (8*u)
                                           : cmv[rt][kt][1] >> (8*(u-4))) & 255u);
                    sf[kt][u] = (byte == (unsigned)g) ? (short)0x3F80 : (short)0;
                }
            // GEMM1': P^T tile, D[m=kf][n=i]: lane=i, kf = mt*16 + ln4*4 + r
            f32x4 pt[4];
            #pragma unroll
            for (int mt = 0; mt < 4; ++mt) pt[mt] = (f32x4){0.f,0.f,0.f,0.f};
            #pragma unroll
            for (int kt2 = 0; kt2 < 2; ++kt2)
                #pragma unroll
                for (int mt = 0; mt < 4; ++mt)
                    pt[mt] = __builtin_amdgcn_mfma_f32_16x16x32_bf16(hf2[mt][kt2], sf[kt2], pt[mt], 0, 0, 0);
            // GEMM2: A-frag = in-lane reshuffle (pi-permuted Wt makes this exact; verified R6)
            #pragma unroll
            for (int kt = 0; kt < 2; ++kt) {
                short8 af;
                #pragma unroll
                for (int r = 0; r < 4; ++r) {
                    af[r]     = (short)f2b(pt[2*kt    ][r]);
                    af[4 + r] = (short)f2b(pt[2*kt + 1][r]);
                }
                #pragma unroll
                for (int nt = 0; nt < 4; ++nt)
                    acc[rt][nt] = __builtin_amdgcn_mfma_f32_16x16x32_bf16(af, bw[kt][nt], acc[rt][nt], 0, 0, 0);
            }
        }
    }
    __syncthreads();                                 // Ht/cm reads all hoisted; safe to alias

    // combine 8 waves into Xs[64][68] f32 (aliases staging region)
    float* Xs = (float*)smem;
    for (int wv = 0; wv < 8; ++wv) {
        if (w == wv) {
            #pragma unroll
            for (int rt = 0; rt < 4; ++rt)
                #pragma unroll
                for (int nt = 0; nt < 4; ++nt)
                    #pragma unroll
                    for (int r = 0; r < 4; ++r) {
                        int row = rt*16 + ln4*4 + r;     // C/D: col=lane&15, row=(lane>>4)*4+reg
                        int col = nt*16 + ln15;
                        if (wv == 0) Xs[row*68 + col]  = acc[rt][nt][r];
                        else         Xs[row*68 + col] += acc[rt][nt][r];
                    }
        }
        __syncthreads();
    }

    // write X + bias (f32x4 coalesced): 512 threads x 8 floats
    {
        const int row = tid >> 3, c0 = (tid & 7)*8;
        float* xg = X + (size_t)(base + row)*64 + c0;
        #pragma unroll
        for (int q = 0; q < 2; ++q) {
            f32x4 v;
            #pragma unroll
            for (int u = 0; u < 4; ++u) v[u] = Xs[row*68 + c0 + q*4 + u] + bvec[c0 + q*4 + u];
            *(f32x4*)(xg + q*4) = v;
        }
    }

    // per-block column sum / sumsq (with bias) over 64 rows
    {
        float* red1 = (float*)(smem + SM_RED);       // [4][64]
        float* red2 = red1 + 256;
        if (tid < 256) {
            int col = tid & 63, rg = tid >> 6;
            float bc = bvec[col], s1 = 0.f, s2 = 0.f;
            for (int ii = 0; ii < 16; ++ii) {
                float xv = Xs[(rg*16 + ii)*68 + col] + bc;
                s1 += xv; s2 += xv*xv;
            }
            red1[rg*64 + col] = s1;
            red2[rg*64 + col] = s2;
        }
        __syncthreads();
        if (tid < 128) {
            int hs = tid >> 6, c2 = tid & 63;
            const float* r0 = hs ? red2 : red1;
            float v = r0[c2] + r0[64 + c2] + r0[128 + c2] + r0[192 + c2];
            partials[(size_t)b*128 + hs*64 + c2] = v; // [block][slot]
        }
    }
}

// ---------------- K2: redundant stats reduce + normalize + ReLU (verified R4) ----------------
__global__ __launch_bounds__(256) void sp_finish(
    float* __restrict__ X, const float* __restrict__ partials,
    const float* __restrict__ gamma, const float* __restrict__ beta)
{
    __shared__ float sp0[128], sp1[128];
    __shared__ float scale[64], shift[64];
    const int b = blockIdx.x, tid = threadIdx.x;

    {   // sum 256 block-partials; coalesced along slot
        const int slot = tid & 127, hb = tid >> 7;
        float v = 0.f;
        const float* p = partials + (size_t)hb*128*128 + slot;
        #pragma unroll 4
        for (int bb = 0; bb < 128; ++bb) v += p[(size_t)bb*128];
        (hb ? sp1 : sp0)[slot] = v;
    }
    __syncthreads();
    if (tid < 64) {
        const float inv_n = 1.0f / (float)NTOT;
        float s1 = sp0[tid] + sp1[tid];
        float s2 = sp0[64 + tid] + sp1[64 + tid];
        float mu  = s1 * inv_n;
        float var = s2 * inv_n - mu*mu;
        float sc  = gamma[tid] / sqrtf(var + EPSV);
        scale[tid] = sc;
        shift[tid] = beta[tid] - mu*sc;
    }
    __syncthreads();
    #pragma unroll
    for (int q = 0; q < 4; ++q) {
        size_t idx4 = (size_t)b*1024 + q*256 + tid;  // f32x4 units
        f32x4 v = ((f32x4*)X)[idx4];
        int c0 = ((int)idx4*4) & 63;
        #pragma unroll
        for (int u = 0; u < 4; ++u)
            v[u] = fmaxf(v[u]*scale[c0 + u] + shift[c0 + u], 0.0f);
        ((f32x4*)X)[idx4] = v;
    }
}

extern "C" void kernel_launch(void* const* d_in, const int* in_sizes, int n_in,
                              void* d_out, int out_size, void* d_ws, size_t ws_size,
                              hipStream_t stream)
{
    const float* h     = (const float*)d_in[0];
    // d_in[1] seq_start_end: provably uniform (reference only uses N//nseq)
    const float* pos   = (const float*)d_in[2];
    const float* W     = (const float*)d_in[3];
    const float* bvec  = (const float*)d_in[4];
    const float* gamma = (const float*)d_in[5];
    const float* beta  = (const float*)d_in[6];

    float* X        = (float*)d_out;
    short* Wt       = (short*)d_ws;                  // 512 KB bf16 W' (k-permuted)
    float* partials = (float*)((char*)d_ws + 524288);// 256*128*4 = 128 KB

    sp_transpose<<<64,   256, 0, stream>>>(W, Wt);
    sp_main     <<<NSEQ, 512, 0, stream>>>(h, pos, Wt, bvec, X, partials);
    sp_finish   <<<NSEQ, 256, 0, stream>>>(X, partials, gamma, beta);
}

// Round 8
// 104.132 us; speedup vs baseline: 1.4463x; 1.1251x over previous
//
#include <hip/hip_runtime.h>
#include <hip/hip_bf16.h>

// SocialPooling round 8: R7 + (a) within-XCD stagger fix (blocks round-robin
// XCDs => b mod 8 constant per XCD; phase by b>>3 instead), (b) double-buffered
// Wt prefetch across the cell loop, (c) 4-step two-buffer wave combine.
// Numerics identical to R6/R7 (pi-permuted Wt, GEMM1' P^T = Ht @ S^T, in-lane
// reshuffle, f32 stats): absmax expected unchanged 0.03125.

#define NSEQ 256
#define NTOT (NSEQ*64)
#define EPSV 1e-5f

typedef __attribute__((ext_vector_type(8))) short short8;
typedef __attribute__((ext_vector_type(4))) float f32x4;
typedef unsigned short ushort_t;

__device__ __forceinline__ ushort_t f2b(float f) {
    __hip_bfloat16 h = __float2bfloat16(f);                 // RNE
    return *reinterpret_cast<ushort_t*>(&h);
}
__device__ __forceinline__ int kperm(int k) {               // slot -> source kf
    return ((k >> 5)*2 + ((k & 7) >> 2))*16 + ((k >> 3) & 3)*4 + (k & 3);
}

// ---------------- K0: W -> bf16 Wt'[g][col][slot] = W[g*64 + pi(slot)][col] ----------------
__global__ __launch_bounds__(256) void sp_transpose(
    const float* __restrict__ W, short* __restrict__ Wt)
{
    __shared__ __align__(16) float Tl[64*68];
    const int b = blockIdx.x, tid = threadIdx.x;
    const float* wg = W + (size_t)b*4096;
    for (int m = 0; m < 4; ++m) {
        int c = m*256 + tid;
        int k = c >> 4, t0 = (c & 15)*4;
        *(f32x4*)(Tl + k*68 + t0) = *(const f32x4*)(wg + k*64 + t0);
    }
    __syncthreads();
    for (int m = 0; m < 2; ++m) {
        int q = m*256 + tid;
        int col = q >> 3, k0 = (q & 7)*8;
        short8 o;
        #pragma unroll
        for (int i2 = 0; i2 < 8; ++i2)
            o[i2] = (short)f2b(Tl[kperm(k0 + i2)*68 + col]);
        *(short8*)(Wt + ((size_t)(b*64 + col)*64 + k0)) = o;
    }
}

// ---------------- K1: main ----------------
// LDS: staging {Ht u16[64][72]@0 9216, cm@9216 4096, pos@13312 512} (aliased by)
//      epilogue {Xs0 f32[64][68]@0, Xs1@17408, red[2][4][64]@34816} tot 36864
#define SM_CM   9216
#define SM_POS  13312
#define SM_XS1  17408
#define SM_RED  34816
#define SM_TOT  36864

__global__ __launch_bounds__(512, 2) void sp_main(
    const float* __restrict__ h, const float* __restrict__ pos,
    const short* __restrict__ Wt, const float* __restrict__ bvec,
    float* __restrict__ X, float* __restrict__ partials)
{
    __shared__ __align__(16) char smem[SM_TOT];
    ushort_t*      Ht = (ushort_t*)(smem);
    unsigned char* cm = (unsigned char*)(smem + SM_CM);
    float*         px = (float*)(smem + SM_POS);
    float*         py = px + 64;

    const int b    = blockIdx.x;        // sequence
    const int base = b * 64;
    const int tid  = threadIdx.x;
    const int lane = tid & 63, w = tid >> 6;      // 8 waves; wave owns cells w*8..w*8+7
    const int ln15 = lane & 15, ln4 = lane >> 4;
    const int xph  = (b >> 3) & 7;      // stagger phase: varies WITHIN an XCD

    if (tid < 64) { px[tid] = pos[(base + tid)*2]; py[tid] = pos[(base + tid)*2 + 1]; }
    // stage H transposed: Ht[kf][j] = bf16(H[j][kf])
    for (int m = 0; m < 2; ++m) {
        int c = m*512 + tid;
        int j = c >> 4, t0 = (c & 15)*4;
        f32x4 v = *(const f32x4*)(h + (size_t)(base + j)*64 + t0);
        #pragma unroll
        for (int u = 0; u < 4; ++u) Ht[(t0 + u)*72 + j] = f2b(v[u]);
    }
    __syncthreads();

    // cellmap: cm[i][j] = cell 0..63 if valid pair else 255 (verified R1..R7)
    for (int m = 0; m < 8; ++m) {
        int p = m*512 + tid;
        int i = p >> 6, j = p & 63;
        unsigned char val = 255;
        if (i != j) {
            float ax = px[i], ay = py[i], ox = px[j], oy = py[j];
            float tlx = ax - 1.0f, tly = ay + 1.0f, brx = ax + 1.0f, bry = ay - 1.0f;
            bool oob = (ox >= brx) | (ox <= tlx) | (oy >= tly) | (oy <= bry);
            if (!oob) {
                int g = (int)(floorf((ox - tlx)*4.0f) + floorf((tly - oy)*4.0f)*8.0f);
                g = g < 0 ? 0 : (g > 63 ? 63 : g);
                val = (unsigned char)g;
            }
        }
        cm[i*64 + j] = val;
    }
    __syncthreads();

    // hoist GEMM1' A-frags (H^T rows) and the full cellmap for all 4 row-tiles
    short8 hf2[4][2];
    #pragma unroll
    for (int mt = 0; mt < 4; ++mt)
        #pragma unroll
        for (int kt2 = 0; kt2 < 2; ++kt2)
            hf2[mt][kt2] = *(const short8*)(Ht + (mt*16 + ln15)*72 + kt2*32 + ln4*8);
    unsigned cmv[4][2][2];
    #pragma unroll
    for (int rt = 0; rt < 4; ++rt)
        #pragma unroll
        for (int kt = 0; kt < 2; ++kt) {
            const unsigned* cp = (const unsigned*)(cm + (rt*16 + ln15)*64 + kt*32 + ln4*8);
            cmv[rt][kt][0] = cp[0]; cmv[rt][kt][1] = cp[1];
        }

    f32x4 acc[4][4];                    // [rt][nt]
    #pragma unroll
    for (int rt = 0; rt < 4; ++rt)
        #pragma unroll
        for (int nt = 0; nt < 4; ++nt) acc[rt][nt] = (f32x4){0.f,0.f,0.f,0.f};

    auto load_cell = [&](short8 (&bw)[2][4], int cidx) {
        const int g = w*8 + ((cidx + xph) & 7);
        const short* wg = Wt + (size_t)g*4096;
        #pragma unroll
        for (int kt = 0; kt < 2; ++kt)
            #pragma unroll
            for (int nt = 0; nt < 4; ++nt)
                bw[kt][nt] = *(const short8*)(wg + (nt*16 + ln15)*64 + kt*32 + ln4*8);
    };
    auto compute_cell = [&](const short8 (&bw)[2][4], int cidx) {
        const int g = w*8 + ((cidx + xph) & 7);
        #pragma unroll
        for (int rt = 0; rt < 4; ++rt) {
            short8 sf[2];
            #pragma unroll
            for (int kt = 0; kt < 2; ++kt)
                #pragma unroll
                for (int u = 0; u < 8; ++u) {
                    unsigned byte = ((u < 4 ? cmv[rt][kt][0] >> (8*u)
                                           : cmv[rt][kt][1] >> (8*(u-4))) & 255u);
                    sf[kt][u] = (byte == (unsigned)g) ? (short)0x3F80 : (short)0;
                }
            f32x4 pt[4];
            #pragma unroll
            for (int mt = 0; mt < 4; ++mt) pt[mt] = (f32x4){0.f,0.f,0.f,0.f};
            #pragma unroll
            for (int kt2 = 0; kt2 < 2; ++kt2)
                #pragma unroll
                for (int mt = 0; mt < 4; ++mt)
                    pt[mt] = __builtin_amdgcn_mfma_f32_16x16x32_bf16(hf2[mt][kt2], sf[kt2], pt[mt], 0, 0, 0);
            #pragma unroll
            for (int kt = 0; kt < 2; ++kt) {
                short8 af;
                #pragma unroll
                for (int r = 0; r < 4; ++r) {
                    af[r]     = (short)f2b(pt[2*kt    ][r]);
                    af[4 + r] = (short)f2b(pt[2*kt + 1][r]);
                }
                #pragma unroll
                for (int nt = 0; nt < 4; ++nt)
                    acc[rt][nt] = __builtin_amdgcn_mfma_f32_16x16x32_bf16(af, bw[kt][nt], acc[rt][nt], 0, 0, 0);
            }
        }
    };

    // software-pipelined cell loop: prefetch next cell's Wt frags during compute
    short8 bwA[2][4], bwB[2][4];
    load_cell(bwA, 0);
    #pragma unroll
    for (int cc = 0; cc < 8; cc += 2) {
        if (cc + 1 < 8) load_cell(bwB, cc + 1);
        compute_cell(bwA, cc);
        if (cc + 2 < 8) load_cell(bwA, cc + 2);
        if (cc + 1 < 8) compute_cell(bwB, cc + 1);
    }
    __syncthreads();                                 // staging reads all hoisted

    // 4-step two-buffer combine: waves 0-3 -> Xs0, waves 4-7 -> Xs1 (parallel)
    float* Xs0 = (float*)smem;
    float* Xs1 = (float*)(smem + SM_XS1);
    for (int step = 0; step < 4; ++step) {
        if ((w & 3) == step) {
            float* Xs = (w < 4) ? Xs0 : Xs1;
            #pragma unroll
            for (int rt = 0; rt < 4; ++rt)
                #pragma unroll
                for (int nt = 0; nt < 4; ++nt)
                    #pragma unroll
                    for (int r = 0; r < 4; ++r) {
                        int row = rt*16 + ln4*4 + r; // C/D: col=lane&15, row=(lane>>4)*4+reg
                        int col = nt*16 + ln15;
                        if (step == 0) Xs[row*68 + col]  = acc[rt][nt][r];
                        else           Xs[row*68 + col] += acc[rt][nt][r];
                    }
        }
        __syncthreads();
    }

    // write X + bias (f32x4 coalesced): 512 threads x 8 floats
    {
        const int row = tid >> 3, c0 = (tid & 7)*8;
        float* xg = X + (size_t)(base + row)*64 + c0;
        #pragma unroll
        for (int q = 0; q < 2; ++q) {
            f32x4 v;
            #pragma unroll
            for (int u = 0; u < 4; ++u) {
                int o = row*68 + c0 + q*4 + u;
                v[u] = Xs0[o] + Xs1[o] + bvec[c0 + q*4 + u];
            }
            *(f32x4*)(xg + q*4) = v;
        }
    }

    // per-block column sum / sumsq (with bias) over 64 rows
    {
        float* red1 = (float*)(smem + SM_RED);       // [4][64]
        float* red2 = red1 + 256;
        if (tid < 256) {
            int col = tid & 63, rg = tid >> 6;
            float bc = bvec[col], s1 = 0.f, s2 = 0.f;
            for (int ii = 0; ii < 16; ++ii) {
                int o = (rg*16 + ii)*68 + col;
                float xv = Xs0[o] + Xs1[o] + bc;
                s1 += xv; s2 += xv*xv;
            }
            red1[rg*64 + col] = s1;
            red2[rg*64 + col] = s2;
        }
        __syncthreads();
        if (tid < 128) {
            int hs = tid >> 6, c2 = tid & 63;
            const float* r0 = hs ? red2 : red1;
            float v = r0[c2] + r0[64 + c2] + r0[128 + c2] + r0[192 + c2];
            partials[(size_t)b*128 + hs*64 + c2] = v; // [block][slot]
        }
    }
}

// ---------------- K2: redundant stats reduce + normalize + ReLU (verified R4+) ----------------
__global__ __launch_bounds__(256) void sp_finish(
    float* __restrict__ X, const float* __restrict__ partials,
    const float* __restrict__ gamma, const float* __restrict__ beta)
{
    __shared__ float sp0[128], sp1[128];
    __shared__ float scale[64], shift[64];
    const int b = blockIdx.x, tid = threadIdx.x;

    {   // sum 256 block-partials; coalesced along slot
        const int slot = tid & 127, hb = tid >> 7;
        float v = 0.f;
        const float* p = partials + (size_t)hb*128*128 + slot;
        #pragma unroll 4
        for (int bb = 0; bb < 128; ++bb) v += p[(size_t)bb*128];
        (hb ? sp1 : sp0)[slot] = v;
    }
    __syncthreads();
    if (tid < 64) {
        const float inv_n = 1.0f / (float)NTOT;
        float s1 = sp0[tid] + sp1[tid];
        float s2 = sp0[64 + tid] + sp1[64 + tid];
        float mu  = s1 * inv_n;
        float var = s2 * inv_n - mu*mu;
        float sc  = gamma[tid] / sqrtf(var + EPSV);
        scale[tid] = sc;
        shift[tid] = beta[tid] - mu*sc;
    }
    __syncthreads();
    #pragma unroll
    for (int q = 0; q < 4; ++q) {
        size_t idx4 = (size_t)b*1024 + q*256 + tid;  // f32x4 units
        f32x4 v = ((f32x4*)X)[idx4];
        int c0 = ((int)idx4*4) & 63;
        #pragma unroll
        for (int u = 0; u < 4; ++u)
            v[u] = fmaxf(v[u]*scale[c0 + u] + shift[c0 + u], 0.0f);
        ((f32x4*)X)[idx4] = v;
    }
}

extern "C" void kernel_launch(void* const* d_in, const int* in_sizes, int n_in,
                              void* d_out, int out_size, void* d_ws, size_t ws_size,
                              hipStream_t stream)
{
    const float* h     = (const float*)d_in[0];
    // d_in[1] seq_start_end: provably uniform (reference only uses N//nseq)
    const float* pos   = (const float*)d_in[2];
    const float* W     = (const float*)d_in[3];
    const float* bvec  = (const float*)d_in[4];
    const float* gamma = (const float*)d_in[5];
    const float* beta  = (const float*)d_in[6];

    float* X        = (float*)d_out;
    short* Wt       = (short*)d_ws;                  // 512 KB bf16 W' (k-permuted)
    float* partials = (float*)((char*)d_ws + 524288);// 256*128*4 = 128 KB

    sp_transpose<<<64,   256, 0, stream>>>(W, Wt);
    sp_main     <<<NSEQ, 512, 0, stream>>>(h, pos, Wt, bvec, X, partials);
    sp_finish   <<<NSEQ, 256, 0, stream>>>(X, partials, gamma, beta);
}